// Round 10
// baseline (69.988 us; speedup 1.0000x reference)
//
#include <hip/hip_runtime.h>

// Problem constants (match reference)
constexpr int cB = 8;
constexpr int cN = 4096;
constexpr int cD = 1024;   // IN_FEATURES
constexpr int cH = 1792;   // HIDDEN_DIM

// Workspace layout (floats)
constexpr size_t OFF_XSUM = 0;                          // 8192
constexpr size_t OFF_KSUM = OFF_XSUM + 8192;            // 14336
constexpr size_t OFF_V    = OFF_KSUM + 14336;           // 8192
constexpr size_t OFF_C    = OFF_V + 8192;               // 8 (pad 64)
constexpr size_t OFF_PART = OFF_C + 64;                 // 1024*1024 = 4 MB
constexpr size_t TOTAL_DET_FLOATS = OFF_PART + 1048576; // ~1.08M floats (~4.3 MB)
constexpr size_t SMALL_FLOATS     = OFF_PART;           // fallback zero region

__device__ __forceinline__ float dot4(float4 a, float4 b) {
    return a.x * b.x + a.y * b.y + a.z * b.z + a.w * b.w;
}

// ---------------------------------------------------------------------------
// k1a (proven): part[b*128+ns][d] = sum of 32 rows of x[b].  x pass 1.
__global__ __launch_bounds__(256) void k1a_partial(const float* __restrict__ x,
                                                   float* __restrict__ part) {
    int bid = blockIdx.x;                 // 0..1023
    int b = bid >> 7, ns = bid & 127;
    const float4* xp = (const float4*)(x + ((size_t)b * cN + (size_t)ns * 32) * cD);
    int t = threadIdx.x;
    float4 acc = make_float4(0.f, 0.f, 0.f, 0.f);
#pragma unroll 8
    for (int r = 0; r < 32; ++r) {
        float4 v = xp[(size_t)r * (cD / 4) + t];
        acc.x += v.x; acc.y += v.y; acc.z += v.z; acc.w += v.w;
    }
    ((float4*)part)[(size_t)bid * (cD / 4) + t] = acc;
}

// k1bF (proven r9): ONE kernel part->xsum. 32 blocks (b,slab) x 512 thr.
__global__ __launch_bounds__(512) void k1bF(const float* __restrict__ part,
                                            float* __restrict__ xsum) {
    __shared__ float4 red[8][64];
    int b = blockIdx.x >> 2, slab = blockIdx.x & 3;
    int w = threadIdx.x >> 6, l = threadIdx.x & 63;
    const float4* p = (const float4*)part + ((size_t)b * 128 + w * 16) * 256 + slab * 64 + l;
    float4 acc = make_float4(0.f, 0.f, 0.f, 0.f);
#pragma unroll
    for (int k = 0; k < 16; ++k) {
        float4 u = p[(size_t)k * 256];
        acc.x += u.x; acc.y += u.y; acc.z += u.z; acc.w += u.w;
    }
    red[w][l] = acc;
    __syncthreads();
    if (w == 0) {
        float4 s = make_float4(0.f, 0.f, 0.f, 0.f);
#pragma unroll
        for (int ww = 0; ww < 8; ++ww) {
            float4 u = red[ww][l];
            s.x += u.x; s.y += u.y; s.z += u.z; s.w += u.w;
        }
        ((float4*)xsum)[(size_t)b * 256 + slab * 64 + l] = s;
    }
}

// ---------------------------------------------------------------------------
// KS (proven): ksum[b][h] = xsum[b]·Wk[h] + N*bk[h].  224 blocks x 512.
__global__ __launch_bounds__(512) void KS(const float* __restrict__ xsum,
                                          const float* __restrict__ Wk,
                                          const float* __restrict__ bk,
                                          float* __restrict__ ksum) {
    int w = threadIdx.x >> 6, l = threadIdx.x & 63;
    int b = w;
    int h0 = blockIdx.x * 8;
    const float4* xs4 = (const float4*)(xsum + (size_t)b * cD);
    float4 xr[4];
#pragma unroll
    for (int j = 0; j < 4; ++j) xr[j] = xs4[l + 64 * j];
    for (int i = 0; i < 8; i += 2) {
        int ha = h0 + i, hb = h0 + i + 1;
        const float4* wka = (const float4*)(Wk + (size_t)ha * cD);
        const float4* wkb = (const float4*)(Wk + (size_t)hb * cD);
        float pa = 0.f, pb = 0.f;
#pragma unroll
        for (int j = 0; j < 4; ++j) {
            pa += dot4(wka[l + 64 * j], xr[j]);
            pb += dot4(wkb[l + 64 * j], xr[j]);
        }
#pragma unroll
        for (int off = 32; off; off >>= 1) {
            pa += __shfl_xor(pa, off);
            pb += __shfl_xor(pb, off);
        }
        if (l == 0) {
            ksum[(size_t)b * cH + ha] = pa + (float)cN * bk[ha];
            ksum[(size_t)b * cH + hb] = pb + (float)cN * bk[hb];
        }
    }
}

// ---------------------------------------------------------------------------
// KV16 (NEW): 16 blocks x 1024 thr; block owns v[all b][dc*64 .. +64) COMPLETELY.
// Stages all ksum (57 KB) in LDS; streams its 448 KB Wq column-slab once
// (sector-complete 256 B row-chunks); 16 h-chunks folded via LDS; writes v
// directly (no vpart, no tail reduce kernel). Block 0 also computes cvec.
__global__ __launch_bounds__(1024) void KV16(const float* __restrict__ ksum,
                                             const float* __restrict__ Wq,
                                             const float* __restrict__ bq,
                                             float* __restrict__ v,
                                             float* __restrict__ cvec) {
    __shared__ float ks_l[cB * cH];        // [b][h]  57 KB
    __shared__ float red[16][cB][64];      // h-chunk partials, 32 KB
    int t = threadIdx.x;
    // stage ksum -> LDS (f4 copy, 3584 f4)
    for (int i = t; i < (cB * cH) / 4; i += 1024)
        ((float4*)ks_l)[i] = ((const float4*)ksum)[i];
    __syncthreads();

    // block 0: cvec[b] = sum_h bq[h]*ksum[b][h]  (waves 0..7, one per b)
    if (blockIdx.x == 0) {
        int w = t >> 6, l = t & 63;
        if (w < cB) {
            float ca = 0.f;
#pragma unroll
            for (int k = 0; k < cH / 64; ++k)   // 28 iters
                ca += bq[l + 64 * k] * ks_l[w * cH + l + 64 * k];
#pragma unroll
            for (int off = 32; off; off >>= 1) ca += __shfl_xor(ca, off);
            if (l == 0) cvec[w] = ca;
        }
    }

    // v-slice: thread (hchunk = t>>6, dl = t&63); d = blockIdx*64 + dl
    int hchunk = t >> 6, dl = t & 63;
    int d = blockIdx.x * 64 + dl;
    float vacc[cB];
#pragma unroll
    for (int b = 0; b < cB; ++b) vacc[b] = 0.f;
    int hbase = hchunk * (cH / 16);        // 112 h per chunk
#pragma unroll 4
    for (int hh = 0; hh < cH / 16; ++hh) {
        int h = hbase + hh;
        float wv = Wq[(size_t)h * cD + d];
#pragma unroll
        for (int b = 0; b < cB; ++b) vacc[b] = fmaf(ks_l[b * cH + h], wv, vacc[b]);
    }
#pragma unroll
    for (int b = 0; b < cB; ++b) red[hchunk][b][dl] = vacc[b];
    __syncthreads();
    // fold 16 chunks: threads 0..511 -> (b, d2)
    if (t < cB * 64) {
        int b = t >> 6, d2 = t & 63;
        float acc = 0.f;
#pragma unroll
        for (int hc = 0; hc < 16; ++hc) acc += red[hc][b][d2];
        v[(size_t)b * cD + blockIdx.x * 64 + d2] = acc;
    }
}

// ---------------------------------------------------------------------------
// k4 (proven r8 shape): scores = (x[b,n]·v[b] + c[b]) * scale.  x pass 2.
__global__ __launch_bounds__(256) void k4_scores(const float* __restrict__ x,
                                                 const float* __restrict__ v,
                                                 const float* __restrict__ cvec,
                                                 float* __restrict__ out) {
    int row0 = blockIdx.x * 16;
    int b = row0 / cN;
    __shared__ float4 vs[cD / 4];
    int t = threadIdx.x;
    vs[t] = ((const float4*)(v + (size_t)b * cD))[t];
    __syncthreads();
    int w = t >> 6, l = t & 63;
    float4 vv[4];
#pragma unroll
    for (int j = 0; j < 4; ++j) vv[j] = vs[l + 64 * j];
    float cb = cvec[b];
    const float scale = (1.0f / 4096.0f) * (1.0f / sqrtf(1792.0f));
    int row = row0 + w * 4;
#pragma unroll
    for (int rp = 0; rp < 2; ++rp) {
        const float4* xa = (const float4*)(x + (size_t)(row + 2 * rp) * cD);
        const float4* xb = (const float4*)(x + (size_t)(row + 2 * rp + 1) * cD);
        float a0 = 0.f, a1 = 0.f;
#pragma unroll
        for (int j = 0; j < 4; ++j) {
            a0 += dot4(xa[l + 64 * j], vv[j]);
            a1 += dot4(xb[l + 64 * j], vv[j]);
        }
#pragma unroll
        for (int off = 32; off; off >>= 1) {
            a0 += __shfl_xor(a0, off);
            a1 += __shfl_xor(a1, off);
        }
        if (l == 0) {
            out[row + 2 * rp]     = (a0 + cb) * scale;
            out[row + 2 * rp + 1] = (a1 + cb) * scale;
        }
    }
}

// ---------------------------------------------------------------------------
// Fallback kernels (ws too small): float atomics, pre-zeroed accumulators.
__global__ __launch_bounds__(256) void k1_atomic(const float* __restrict__ x,
                                                 float* __restrict__ xsum) {
    int bid = blockIdx.x;
    int b = bid >> 7, ns = bid & 127;
    const float4* xp = (const float4*)(x + ((size_t)b * cN + (size_t)ns * 32) * cD);
    int t = threadIdx.x;
    float4 acc = make_float4(0.f, 0.f, 0.f, 0.f);
    for (int r = 0; r < 32; ++r) {
        float4 v = xp[(size_t)r * (cD / 4) + t];
        acc.x += v.x; acc.y += v.y; acc.z += v.z; acc.w += v.w;
    }
    float* dst = xsum + (size_t)b * cD + t * 4;
    atomicAdd(dst + 0, acc.x);
    atomicAdd(dst + 1, acc.y);
    atomicAdd(dst + 2, acc.z);
    atomicAdd(dst + 3, acc.w);
}

__global__ __launch_bounds__(512) void k23_atomic(const float* __restrict__ xsum,
                                                  const float* __restrict__ Wk,
                                                  const float* __restrict__ bk,
                                                  const float* __restrict__ Wq,
                                                  const float* __restrict__ bq,
                                                  float* __restrict__ v,
                                                  float* __restrict__ cvec) {
    int w = threadIdx.x >> 6, l = threadIdx.x & 63;
    int b = w;
    int h0 = blockIdx.x * 8;
    const float4* xs4 = (const float4*)(xsum + (size_t)b * cD);
    float4 xr[4];
#pragma unroll
    for (int j = 0; j < 4; ++j) xr[j] = xs4[l + 64 * j];
    float4 vacc[4];
#pragma unroll
    for (int j = 0; j < 4; ++j) vacc[j] = make_float4(0.f, 0.f, 0.f, 0.f);
    float cacc = 0.f;
    for (int i = 0; i < 8; ++i) {
        int h = h0 + i;
        const float4* wk4 = (const float4*)(Wk + (size_t)h * cD);
        float pd = 0.f;
#pragma unroll
        for (int j = 0; j < 4; ++j) pd += dot4(wk4[l + 64 * j], xr[j]);
#pragma unroll
        for (int off = 32; off; off >>= 1) pd += __shfl_xor(pd, off);
        float ks = pd + (float)cN * bk[h];
        cacc += bq[h] * ks;
        const float4* wq4 = (const float4*)(Wq + (size_t)h * cD);
#pragma unroll
        for (int j = 0; j < 4; ++j) {
            float4 q = wq4[l + 64 * j];
            vacc[j].x = fmaf(q.x, ks, vacc[j].x);
            vacc[j].y = fmaf(q.y, ks, vacc[j].y);
            vacc[j].z = fmaf(q.z, ks, vacc[j].z);
            vacc[j].w = fmaf(q.w, ks, vacc[j].w);
        }
    }
    float* vb = v + (size_t)b * cD;
#pragma unroll
    for (int j = 0; j < 4; ++j) {
        int d = 4 * (l + 64 * j);
        atomicAdd(vb + d + 0, vacc[j].x);
        atomicAdd(vb + d + 1, vacc[j].y);
        atomicAdd(vb + d + 2, vacc[j].z);
        atomicAdd(vb + d + 3, vacc[j].w);
    }
    if (l == 0) atomicAdd(&cvec[b], cacc);
}

// ---------------------------------------------------------------------------
extern "C" void kernel_launch(void* const* d_in, const int* in_sizes, int n_in,
                              void* d_out, int out_size, void* d_ws, size_t ws_size,
                              hipStream_t stream) {
    const float* x  = (const float*)d_in[0];
    const float* Wq = (const float*)d_in[1];
    const float* bq = (const float*)d_in[2];
    const float* Wk = (const float*)d_in[3];
    const float* bk = (const float*)d_in[4];
    float* out = (float*)d_out;
    float* ws  = (float*)d_ws;

    float* xsum = ws + OFF_XSUM;
    float* ksum = ws + OFF_KSUM;
    float* v    = ws + OFF_V;
    float* cvec = ws + OFF_C;
    float* part = ws + OFF_PART;

    const bool det = ws_size >= TOTAL_DET_FLOATS * sizeof(float);

    if (det) {
        k1a_partial<<<1024, 256, 0, stream>>>(x, part);       // x pass 1 (~17-20us)
        k1bF<<<32, 512, 0, stream>>>(part, xsum);             // part -> xsum
        KS<<<cH / 8, 512, 0, stream>>>(xsum, Wk, bk, ksum);   // Wk once
        KV16<<<16, 1024, 0, stream>>>(ksum, Wq, bq, v, cvec); // Wq once -> v,c direct
        k4_scores<<<(cB * cN) / 16, 256, 0, stream>>>(x, v, cvec, out); // x pass 2
    } else {
        hipMemsetAsync(d_ws, 0, SMALL_FLOATS * sizeof(float), stream);
        k1_atomic<<<1024, 256, 0, stream>>>(x, xsum);
        k23_atomic<<<cH / 8, 512, 0, stream>>>(xsum, Wk, bk, Wq, bq, v, cvec);
        k4_scores<<<(cB * cN) / 16, 256, 0, stream>>>(x, v, cvec, out);
    }
}

// Round 11
// 63.329 us; speedup vs baseline: 1.1052x; 1.1052x over previous
//
#include <hip/hip_runtime.h>

// Problem constants (match reference)
constexpr int cB = 8;
constexpr int cN = 4096;
constexpr int cD = 1024;   // IN_FEATURES
constexpr int cH = 1792;   // HIDDEN_DIM

// Workspace layout (floats)
constexpr size_t OFF_XSUM = 0;                          // 8192
constexpr size_t OFF_KSUM = OFF_XSUM + 8192;            // 14336
constexpr size_t OFF_V    = OFF_KSUM + 14336;           // 8192
constexpr size_t OFF_C    = OFF_V + 8192;               // 8 (pad 64)
constexpr size_t OFF_PART = OFF_C + 64;                 // 1024*1024 = 4 MB
constexpr size_t TOTAL_DET_FLOATS = OFF_PART + 1048576; // ~1.08M floats (~4.3 MB)
constexpr size_t SMALL_FLOATS     = OFF_PART;           // fallback zero region

__device__ __forceinline__ float dot4(float4 a, float4 b) {
    return a.x * b.x + a.y * b.y + a.z * b.z + a.w * b.w;
}

// ---------------------------------------------------------------------------
// k1a (proven): part[b*128+ns][d] = sum of 32 rows of x[b].  x pass 1.
__global__ __launch_bounds__(256) void k1a_partial(const float* __restrict__ x,
                                                   float* __restrict__ part) {
    int bid = blockIdx.x;                 // 0..1023
    int b = bid >> 7, ns = bid & 127;
    const float4* xp = (const float4*)(x + ((size_t)b * cN + (size_t)ns * 32) * cD);
    int t = threadIdx.x;
    float4 acc = make_float4(0.f, 0.f, 0.f, 0.f);
#pragma unroll 8
    for (int r = 0; r < 32; ++r) {
        float4 v = xp[(size_t)r * (cD / 4) + t];
        acc.x += v.x; acc.y += v.y; acc.z += v.z; acc.w += v.w;
    }
    ((float4*)part)[(size_t)bid * (cD / 4) + t] = acc;
}

// k1bF (proven): ONE kernel part->xsum. 32 blocks (b,slab) x 512 thr.
__global__ __launch_bounds__(512) void k1bF(const float* __restrict__ part,
                                            float* __restrict__ xsum) {
    __shared__ float4 red[8][64];
    int b = blockIdx.x >> 2, slab = blockIdx.x & 3;
    int w = threadIdx.x >> 6, l = threadIdx.x & 63;
    const float4* p = (const float4*)part + ((size_t)b * 128 + w * 16) * 256 + slab * 64 + l;
    float4 acc = make_float4(0.f, 0.f, 0.f, 0.f);
#pragma unroll
    for (int k = 0; k < 16; ++k) {
        float4 u = p[(size_t)k * 256];
        acc.x += u.x; acc.y += u.y; acc.z += u.z; acc.w += u.w;
    }
    red[w][l] = acc;
    __syncthreads();
    if (w == 0) {
        float4 s = make_float4(0.f, 0.f, 0.f, 0.f);
#pragma unroll
        for (int ww = 0; ww < 8; ++ww) {
            float4 u = red[ww][l];
            s.x += u.x; s.y += u.y; s.z += u.z; s.w += u.w;
        }
        ((float4*)xsum)[(size_t)b * 256 + slab * 64 + l] = s;
    }
}

// ---------------------------------------------------------------------------
// KS (proven): ksum[b][h] = xsum[b]·Wk[h] + N*bk[h].  224 blocks x 512.
__global__ __launch_bounds__(512) void KS(const float* __restrict__ xsum,
                                          const float* __restrict__ Wk,
                                          const float* __restrict__ bk,
                                          float* __restrict__ ksum) {
    int w = threadIdx.x >> 6, l = threadIdx.x & 63;
    int b = w;
    int h0 = blockIdx.x * 8;
    const float4* xs4 = (const float4*)(xsum + (size_t)b * cD);
    float4 xr[4];
#pragma unroll
    for (int j = 0; j < 4; ++j) xr[j] = xs4[l + 64 * j];
    for (int i = 0; i < 8; i += 2) {
        int ha = h0 + i, hb = h0 + i + 1;
        const float4* wka = (const float4*)(Wk + (size_t)ha * cD);
        const float4* wkb = (const float4*)(Wk + (size_t)hb * cD);
        float pa = 0.f, pb = 0.f;
#pragma unroll
        for (int j = 0; j < 4; ++j) {
            pa += dot4(wka[l + 64 * j], xr[j]);
            pb += dot4(wkb[l + 64 * j], xr[j]);
        }
#pragma unroll
        for (int off = 32; off; off >>= 1) {
            pa += __shfl_xor(pa, off);
            pb += __shfl_xor(pb, off);
        }
        if (l == 0) {
            ksum[(size_t)b * cH + ha] = pa + (float)cN * bk[ha];
            ksum[(size_t)b * cH + hb] = pb + (float)cN * bk[hb];
        }
    }
}

// ---------------------------------------------------------------------------
// KV64 (NEW): 64 blocks x 1024 thr; block g owns v[all b][g*16 .. +16) fully.
// Stages all ksum (57 KB) in LDS; streams its 114 KB Wq column-slab once
// (1792 rows x 64 B = full sectors); thread (hc,dl) accumulates 28 h x 8 b in
// registers; 64 h-chunks folded via LDS; writes v directly. Block 0: cvec.
__global__ __launch_bounds__(1024) void KV64(const float* __restrict__ ksum,
                                             const float* __restrict__ Wq,
                                             const float* __restrict__ bq,
                                             float* __restrict__ v,
                                             float* __restrict__ cvec) {
    __shared__ float ks_l[cB * cH];        // [b][h]  57 KB
    __shared__ float red[64][cB][16];      // h-chunk partials, 32 KB
    int t = threadIdx.x;
    // stage ksum -> LDS (f4 copy, 3584 f4)
    for (int i = t; i < (cB * cH) / 4; i += 1024)
        ((float4*)ks_l)[i] = ((const float4*)ksum)[i];
    __syncthreads();

    // block 0: cvec[b] = sum_h bq[h]*ksum[b][h]  (waves 0..7, one per b)
    if (blockIdx.x == 0) {
        int w = t >> 6, l = t & 63;
        if (w < cB) {
            float ca = 0.f;
#pragma unroll
            for (int k = 0; k < cH / 64; ++k)   // 28 iters
                ca += bq[l + 64 * k] * ks_l[w * cH + l + 64 * k];
#pragma unroll
            for (int off = 32; off; off >>= 1) ca += __shfl_xor(ca, off);
            if (l == 0) cvec[w] = ca;
        }
    }

    // v-slice: thread (hc = t>>4 in 0..63, dl = t&15); d = blockIdx*16 + dl
    int hc = t >> 4, dl = t & 15;
    int d = blockIdx.x * 16 + dl;
    float vacc[cB];
#pragma unroll
    for (int b = 0; b < cB; ++b) vacc[b] = 0.f;
    int hbase = hc * (cH / 64);            // 28 h per chunk
#pragma unroll 4
    for (int hh = 0; hh < cH / 64; ++hh) {
        int h = hbase + hh;
        float wv = Wq[(size_t)h * cD + d];
#pragma unroll
        for (int b = 0; b < cB; ++b) vacc[b] = fmaf(ks_l[b * cH + h], wv, vacc[b]);
    }
#pragma unroll
    for (int b = 0; b < cB; ++b) red[hc][b][dl] = vacc[b];
    __syncthreads();
    // fold 64 chunks: threads 0..127 -> (b, d2)
    if (t < cB * 16) {
        int b = t >> 4, d2 = t & 15;
        float acc = 0.f;
#pragma unroll
        for (int hcc = 0; hcc < 64; ++hcc) acc += red[hcc][b][d2];
        v[(size_t)b * cD + blockIdx.x * 16 + d2] = acc;
    }
}

// ---------------------------------------------------------------------------
// k4 (proven r8 shape): scores = (x[b,n]·v[b] + c[b]) * scale.  x pass 2.
__global__ __launch_bounds__(256) void k4_scores(const float* __restrict__ x,
                                                 const float* __restrict__ v,
                                                 const float* __restrict__ cvec,
                                                 float* __restrict__ out) {
    int row0 = blockIdx.x * 16;
    int b = row0 / cN;
    __shared__ float4 vs[cD / 4];
    int t = threadIdx.x;
    vs[t] = ((const float4*)(v + (size_t)b * cD))[t];
    __syncthreads();
    int w = t >> 6, l = t & 63;
    float4 vv[4];
#pragma unroll
    for (int j = 0; j < 4; ++j) vv[j] = vs[l + 64 * j];
    float cb = cvec[b];
    const float scale = (1.0f / 4096.0f) * (1.0f / sqrtf(1792.0f));
    int row = row0 + w * 4;
#pragma unroll
    for (int rp = 0; rp < 2; ++rp) {
        const float4* xa = (const float4*)(x + (size_t)(row + 2 * rp) * cD);
        const float4* xb = (const float4*)(x + (size_t)(row + 2 * rp + 1) * cD);
        float a0 = 0.f, a1 = 0.f;
#pragma unroll
        for (int j = 0; j < 4; ++j) {
            a0 += dot4(xa[l + 64 * j], vv[j]);
            a1 += dot4(xb[l + 64 * j], vv[j]);
        }
#pragma unroll
        for (int off = 32; off; off >>= 1) {
            a0 += __shfl_xor(a0, off);
            a1 += __shfl_xor(a1, off);
        }
        if (l == 0) {
            out[row + 2 * rp]     = (a0 + cb) * scale;
            out[row + 2 * rp + 1] = (a1 + cb) * scale;
        }
    }
}

// ---------------------------------------------------------------------------
// Fallback kernels (ws too small): float atomics, pre-zeroed accumulators.
__global__ __launch_bounds__(256) void k1_atomic(const float* __restrict__ x,
                                                 float* __restrict__ xsum) {
    int bid = blockIdx.x;
    int b = bid >> 7, ns = bid & 127;
    const float4* xp = (const float4*)(x + ((size_t)b * cN + (size_t)ns * 32) * cD);
    int t = threadIdx.x;
    float4 acc = make_float4(0.f, 0.f, 0.f, 0.f);
    for (int r = 0; r < 32; ++r) {
        float4 v = xp[(size_t)r * (cD / 4) + t];
        acc.x += v.x; acc.y += v.y; acc.z += v.z; acc.w += v.w;
    }
    float* dst = xsum + (size_t)b * cD + t * 4;
    atomicAdd(dst + 0, acc.x);
    atomicAdd(dst + 1, acc.y);
    atomicAdd(dst + 2, acc.z);
    atomicAdd(dst + 3, acc.w);
}

__global__ __launch_bounds__(512) void k23_atomic(const float* __restrict__ xsum,
                                                  const float* __restrict__ Wk,
                                                  const float* __restrict__ bk,
                                                  const float* __restrict__ Wq,
                                                  const float* __restrict__ bq,
                                                  float* __restrict__ v,
                                                  float* __restrict__ cvec) {
    int w = threadIdx.x >> 6, l = threadIdx.x & 63;
    int b = w;
    int h0 = blockIdx.x * 8;
    const float4* xs4 = (const float4*)(xsum + (size_t)b * cD);
    float4 xr[4];
#pragma unroll
    for (int j = 0; j < 4; ++j) xr[j] = xs4[l + 64 * j];
    float4 vacc[4];
#pragma unroll
    for (int j = 0; j < 4; ++j) vacc[j] = make_float4(0.f, 0.f, 0.f, 0.f);
    float cacc = 0.f;
    for (int i = 0; i < 8; ++i) {
        int h = h0 + i;
        const float4* wk4 = (const float4*)(Wk + (size_t)h * cD);
        float pd = 0.f;
#pragma unroll
        for (int j = 0; j < 4; ++j) pd += dot4(wk4[l + 64 * j], xr[j]);
#pragma unroll
        for (int off = 32; off; off >>= 1) pd += __shfl_xor(pd, off);
        float ks = pd + (float)cN * bk[h];
        cacc += bq[h] * ks;
        const float4* wq4 = (const float4*)(Wq + (size_t)h * cD);
#pragma unroll
        for (int j = 0; j < 4; ++j) {
            float4 q = wq4[l + 64 * j];
            vacc[j].x = fmaf(q.x, ks, vacc[j].x);
            vacc[j].y = fmaf(q.y, ks, vacc[j].y);
            vacc[j].z = fmaf(q.z, ks, vacc[j].z);
            vacc[j].w = fmaf(q.w, ks, vacc[j].w);
        }
    }
    float* vb = v + (size_t)b * cD;
#pragma unroll
    for (int j = 0; j < 4; ++j) {
        int d = 4 * (l + 64 * j);
        atomicAdd(vb + d + 0, vacc[j].x);
        atomicAdd(vb + d + 1, vacc[j].y);
        atomicAdd(vb + d + 2, vacc[j].z);
        atomicAdd(vb + d + 3, vacc[j].w);
    }
    if (l == 0) atomicAdd(&cvec[b], cacc);
}

// ---------------------------------------------------------------------------
extern "C" void kernel_launch(void* const* d_in, const int* in_sizes, int n_in,
                              void* d_out, int out_size, void* d_ws, size_t ws_size,
                              hipStream_t stream) {
    const float* x  = (const float*)d_in[0];
    const float* Wq = (const float*)d_in[1];
    const float* bq = (const float*)d_in[2];
    const float* Wk = (const float*)d_in[3];
    const float* bk = (const float*)d_in[4];
    float* out = (float*)d_out;
    float* ws  = (float*)d_ws;

    float* xsum = ws + OFF_XSUM;
    float* ksum = ws + OFF_KSUM;
    float* v    = ws + OFF_V;
    float* cvec = ws + OFF_C;
    float* part = ws + OFF_PART;

    const bool det = ws_size >= TOTAL_DET_FLOATS * sizeof(float);

    if (det) {
        k1a_partial<<<1024, 256, 0, stream>>>(x, part);       // x pass 1
        k1bF<<<32, 512, 0, stream>>>(part, xsum);             // part -> xsum
        KS<<<cH / 8, 512, 0, stream>>>(xsum, Wk, bk, ksum);   // Wk once, 224 blocks
        KV64<<<64, 1024, 0, stream>>>(ksum, Wq, bq, v, cvec); // Wq once, 64 blocks -> v,c
        k4_scores<<<(cB * cN) / 16, 256, 0, stream>>>(x, v, cvec, out); // x pass 2
    } else {
        hipMemsetAsync(d_ws, 0, SMALL_FLOATS * sizeof(float), stream);
        k1_atomic<<<1024, 256, 0, stream>>>(x, xsum);
        k23_atomic<<<cH / 8, 512, 0, stream>>>(xsum, Wk, bk, Wq, bq, v, cvec);
        k4_scores<<<(cB * cN) / 16, 256, 0, stream>>>(x, v, cvec, out);
    }
}

// Round 12
// 62.798 us; speedup vs baseline: 1.1145x; 1.0085x over previous
//
#include <hip/hip_runtime.h>

// Problem constants (match reference)
constexpr int cB = 8;
constexpr int cN = 4096;
constexpr int cD = 1024;   // IN_FEATURES
constexpr int cH = 1792;   // HIDDEN_DIM

// Workspace layout (floats)
constexpr size_t OFF_XSUM = 0;                          // 8192
constexpr size_t OFF_KSUM = OFF_XSUM + 8192;            // 14336
constexpr size_t OFF_V    = OFF_KSUM + 14336;           // 8192
constexpr size_t OFF_C    = OFF_V + 8192;               // 8 (pad 64)
constexpr size_t OFF_PART = OFF_C + 64;                 // 1024*1024 = 4 MB
constexpr size_t TOTAL_DET_FLOATS = OFF_PART + 1048576; // ~1.08M floats (~4.3 MB)
constexpr size_t SMALL_FLOATS     = OFF_PART;           // fallback zero region

__device__ __forceinline__ float dot4(float4 a, float4 b) {
    return a.x * b.x + a.y * b.y + a.z * b.z + a.w * b.w;
}

// ---------------------------------------------------------------------------
// k1a (proven): part[b*128+ns][d] = sum of 32 rows of x[b].  x pass 1 (HBM).
__global__ __launch_bounds__(256) void k1a_partial(const float* __restrict__ x,
                                                   float* __restrict__ part) {
    int bid = blockIdx.x;                 // 0..1023
    int b = bid >> 7, ns = bid & 127;
    const float4* xp = (const float4*)(x + ((size_t)b * cN + (size_t)ns * 32) * cD);
    int t = threadIdx.x;
    float4 acc = make_float4(0.f, 0.f, 0.f, 0.f);
#pragma unroll 8
    for (int r = 0; r < 32; ++r) {
        float4 v = xp[(size_t)r * (cD / 4) + t];
        acc.x += v.x; acc.y += v.y; acc.z += v.z; acc.w += v.w;
    }
    ((float4*)part)[(size_t)bid * (cD / 4) + t] = acc;
}

// k1bW (NEW, wide): part -> xsum on 256 blocks (full-machine width).
// Block g = (b = g>>5, dchunk = g&31). Reads 128 rows x 128 B contiguous
// (2 full sectors/row, zero amplification, 16 KB/block); LDS fold; writes
// 32 floats of xsum.  Work ~ 4 MB / (256 CU x 28 GB/s) ~ 0.6 us.
__global__ __launch_bounds__(256) void k1bW(const float* __restrict__ part,
                                            float* __restrict__ xsum) {
    __shared__ float4 red[32][8];
    int g = blockIdx.x;
    int b = g >> 5, dchunk = g & 31;
    int t = threadIdx.x;
    int col = t & 7, rgrp = t >> 3;       // f4-col 0..7, row-group 0..31
    const float4* p = (const float4*)part + ((size_t)b * 128 + rgrp) * 256 + dchunk * 8 + col;
    float4 acc = make_float4(0.f, 0.f, 0.f, 0.f);
#pragma unroll
    for (int k = 0; k < 4; ++k) {         // rows rgrp, rgrp+32, +64, +96
        float4 u = p[(size_t)(32 * k) * 256];
        acc.x += u.x; acc.y += u.y; acc.z += u.z; acc.w += u.w;
    }
    red[rgrp][col] = acc;
    __syncthreads();
    if (rgrp == 0) {                      // threads 0..7: fold 32 row-groups
        float4 s = red[0][col];
#pragma unroll
        for (int k = 1; k < 32; ++k) {
            float4 u = red[k][col];
            s.x += u.x; s.y += u.y; s.z += u.z; s.w += u.w;
        }
        ((float4*)xsum)[(size_t)b * 256 + dchunk * 8 + col] = s;
    }
}

// ---------------------------------------------------------------------------
// KS (proven): ksum[b][h] = xsum[b]·Wk[h] + N*bk[h].  224 blocks x 512.
__global__ __launch_bounds__(512) void KS(const float* __restrict__ xsum,
                                          const float* __restrict__ Wk,
                                          const float* __restrict__ bk,
                                          float* __restrict__ ksum) {
    int w = threadIdx.x >> 6, l = threadIdx.x & 63;
    int b = w;
    int h0 = blockIdx.x * 8;
    const float4* xs4 = (const float4*)(xsum + (size_t)b * cD);
    float4 xr[4];
#pragma unroll
    for (int j = 0; j < 4; ++j) xr[j] = xs4[l + 64 * j];
    for (int i = 0; i < 8; i += 2) {
        int ha = h0 + i, hb = h0 + i + 1;
        const float4* wka = (const float4*)(Wk + (size_t)ha * cD);
        const float4* wkb = (const float4*)(Wk + (size_t)hb * cD);
        float pa = 0.f, pb = 0.f;
#pragma unroll
        for (int j = 0; j < 4; ++j) {
            pa += dot4(wka[l + 64 * j], xr[j]);
            pb += dot4(wkb[l + 64 * j], xr[j]);
        }
#pragma unroll
        for (int off = 32; off; off >>= 1) {
            pa += __shfl_xor(pa, off);
            pb += __shfl_xor(pb, off);
        }
        if (l == 0) {
            ksum[(size_t)b * cH + ha] = pa + (float)cN * bk[ha];
            ksum[(size_t)b * cH + hb] = pb + (float)cN * bk[hb];
        }
    }
}

// ---------------------------------------------------------------------------
// KV64 (proven r11): 64 blocks x 1024 thr; block g owns v[all b][g*16..+16).
__global__ __launch_bounds__(1024) void KV64(const float* __restrict__ ksum,
                                             const float* __restrict__ Wq,
                                             const float* __restrict__ bq,
                                             float* __restrict__ v,
                                             float* __restrict__ cvec) {
    __shared__ float ks_l[cB * cH];        // [b][h]  57 KB
    __shared__ float red[64][cB][16];      // h-chunk partials, 32 KB
    int t = threadIdx.x;
    for (int i = t; i < (cB * cH) / 4; i += 1024)
        ((float4*)ks_l)[i] = ((const float4*)ksum)[i];
    __syncthreads();

    if (blockIdx.x == 0) {                 // cvec[b] = bq·ksum[b]
        int w = t >> 6, l = t & 63;
        if (w < cB) {
            float ca = 0.f;
#pragma unroll
            for (int k = 0; k < cH / 64; ++k)
                ca += bq[l + 64 * k] * ks_l[w * cH + l + 64 * k];
#pragma unroll
            for (int off = 32; off; off >>= 1) ca += __shfl_xor(ca, off);
            if (l == 0) cvec[w] = ca;
        }
    }

    int hc = t >> 4, dl = t & 15;
    int d = blockIdx.x * 16 + dl;
    float vacc[cB];
#pragma unroll
    for (int b = 0; b < cB; ++b) vacc[b] = 0.f;
    int hbase = hc * (cH / 64);            // 28 h per chunk
#pragma unroll 4
    for (int hh = 0; hh < cH / 64; ++hh) {
        int h = hbase + hh;
        float wv = Wq[(size_t)h * cD + d];
#pragma unroll
        for (int b = 0; b < cB; ++b) vacc[b] = fmaf(ks_l[b * cH + h], wv, vacc[b]);
    }
#pragma unroll
    for (int b = 0; b < cB; ++b) red[hc][b][dl] = vacc[b];
    __syncthreads();
    if (t < cB * 16) {
        int b = t >> 4, d2 = t & 15;
        float acc = 0.f;
#pragma unroll
        for (int hcc = 0; hcc < 64; ++hcc) acc += red[hcc][b][d2];
        v[(size_t)b * cD + blockIdx.x * 16 + d2] = acc;
    }
}

// ---------------------------------------------------------------------------
// k4 (proven): scores = (x[b,n]·v[b] + c[b]) * scale.  x pass 2 (L3-warm).
__global__ __launch_bounds__(256) void k4_scores(const float* __restrict__ x,
                                                 const float* __restrict__ v,
                                                 const float* __restrict__ cvec,
                                                 float* __restrict__ out) {
    int row0 = blockIdx.x * 16;
    int b = row0 / cN;
    __shared__ float4 vs[cD / 4];
    int t = threadIdx.x;
    vs[t] = ((const float4*)(v + (size_t)b * cD))[t];
    __syncthreads();
    int w = t >> 6, l = t & 63;
    float4 vv[4];
#pragma unroll
    for (int j = 0; j < 4; ++j) vv[j] = vs[l + 64 * j];
    float cb = cvec[b];
    const float scale = (1.0f / 4096.0f) * (1.0f / sqrtf(1792.0f));
    int row = row0 + w * 4;
#pragma unroll
    for (int rp = 0; rp < 2; ++rp) {
        const float4* xa = (const float4*)(x + (size_t)(row + 2 * rp) * cD);
        const float4* xb = (const float4*)(x + (size_t)(row + 2 * rp + 1) * cD);
        float a0 = 0.f, a1 = 0.f;
#pragma unroll
        for (int j = 0; j < 4; ++j) {
            a0 += dot4(xa[l + 64 * j], vv[j]);
            a1 += dot4(xb[l + 64 * j], vv[j]);
        }
#pragma unroll
        for (int off = 32; off; off >>= 1) {
            a0 += __shfl_xor(a0, off);
            a1 += __shfl_xor(a1, off);
        }
        if (l == 0) {
            out[row + 2 * rp]     = (a0 + cb) * scale;
            out[row + 2 * rp + 1] = (a1 + cb) * scale;
        }
    }
}

// ---------------------------------------------------------------------------
// Fallback kernels (ws too small): float atomics, pre-zeroed accumulators.
__global__ __launch_bounds__(256) void k1_atomic(const float* __restrict__ x,
                                                 float* __restrict__ xsum) {
    int bid = blockIdx.x;
    int b = bid >> 7, ns = bid & 127;
    const float4* xp = (const float4*)(x + ((size_t)b * cN + (size_t)ns * 32) * cD);
    int t = threadIdx.x;
    float4 acc = make_float4(0.f, 0.f, 0.f, 0.f);
    for (int r = 0; r < 32; ++r) {
        float4 v = xp[(size_t)r * (cD / 4) + t];
        acc.x += v.x; acc.y += v.y; acc.z += v.z; acc.w += v.w;
    }
    float* dst = xsum + (size_t)b * cD + t * 4;
    atomicAdd(dst + 0, acc.x);
    atomicAdd(dst + 1, acc.y);
    atomicAdd(dst + 2, acc.z);
    atomicAdd(dst + 3, acc.w);
}

__global__ __launch_bounds__(512) void k23_atomic(const float* __restrict__ xsum,
                                                  const float* __restrict__ Wk,
                                                  const float* __restrict__ bk,
                                                  const float* __restrict__ Wq,
                                                  const float* __restrict__ bq,
                                                  float* __restrict__ v,
                                                  float* __restrict__ cvec) {
    int w = threadIdx.x >> 6, l = threadIdx.x & 63;
    int b = w;
    int h0 = blockIdx.x * 8;
    const float4* xs4 = (const float4*)(xsum + (size_t)b * cD);
    float4 xr[4];
#pragma unroll
    for (int j = 0; j < 4; ++j) xr[j] = xs4[l + 64 * j];
    float4 vacc[4];
#pragma unroll
    for (int j = 0; j < 4; ++j) vacc[j] = make_float4(0.f, 0.f, 0.f, 0.f);
    float cacc = 0.f;
    for (int i = 0; i < 8; ++i) {
        int h = h0 + i;
        const float4* wk4 = (const float4*)(Wk + (size_t)h * cD);
        float pd = 0.f;
#pragma unroll
        for (int j = 0; j < 4; ++j) pd += dot4(wk4[l + 64 * j], xr[j]);
#pragma unroll
        for (int off = 32; off; off >>= 1) pd += __shfl_xor(pd, off);
        float ks = pd + (float)cN * bk[h];
        cacc += bq[h] * ks;
        const float4* wq4 = (const float4*)(Wq + (size_t)h * cD);
#pragma unroll
        for (int j = 0; j < 4; ++j) {
            float4 q = wq4[l + 64 * j];
            vacc[j].x = fmaf(q.x, ks, vacc[j].x);
            vacc[j].y = fmaf(q.y, ks, vacc[j].y);
            vacc[j].z = fmaf(q.z, ks, vacc[j].z);
            vacc[j].w = fmaf(q.w, ks, vacc[j].w);
        }
    }
    float* vb = v + (size_t)b * cD;
#pragma unroll
    for (int j = 0; j < 4; ++j) {
        int d = 4 * (l + 64 * j);
        atomicAdd(vb + d + 0, vacc[j].x);
        atomicAdd(vb + d + 1, vacc[j].y);
        atomicAdd(vb + d + 2, vacc[j].z);
        atomicAdd(vb + d + 3, vacc[j].w);
    }
    if (l == 0) atomicAdd(&cvec[b], cacc);
}

// ---------------------------------------------------------------------------
extern "C" void kernel_launch(void* const* d_in, const int* in_sizes, int n_in,
                              void* d_out, int out_size, void* d_ws, size_t ws_size,
                              hipStream_t stream) {
    const float* x  = (const float*)d_in[0];
    const float* Wq = (const float*)d_in[1];
    const float* bq = (const float*)d_in[2];
    const float* Wk = (const float*)d_in[3];
    const float* bk = (const float*)d_in[4];
    float* out = (float*)d_out;
    float* ws  = (float*)d_ws;

    float* xsum = ws + OFF_XSUM;
    float* ksum = ws + OFF_KSUM;
    float* v    = ws + OFF_V;
    float* cvec = ws + OFF_C;
    float* part = ws + OFF_PART;

    const bool det = ws_size >= TOTAL_DET_FLOATS * sizeof(float);

    if (det) {
        k1a_partial<<<1024, 256, 0, stream>>>(x, part);       // x pass 1 (HBM roofline)
        k1bW<<<256, 256, 0, stream>>>(part, xsum);            // WIDE part -> xsum
        KS<<<cH / 8, 512, 0, stream>>>(xsum, Wk, bk, ksum);   // Wk once, 224 blocks
        KV64<<<64, 1024, 0, stream>>>(ksum, Wq, bq, v, cvec); // Wq once, 64 blocks
        k4_scores<<<(cB * cN) / 16, 256, 0, stream>>>(x, v, cvec, out); // x pass 2 (L3)
    } else {
        hipMemsetAsync(d_ws, 0, SMALL_FLOATS * sizeof(float), stream);
        k1_atomic<<<1024, 256, 0, stream>>>(x, xsum);
        k23_atomic<<<cH / 8, 512, 0, stream>>>(xsum, Wk, bk, Wq, bq, v, cvec);
        k4_scores<<<(cB * cN) / 16, 256, 0, stream>>>(x, v, cvec, out);
    }
}